// Round 1
// baseline (103.596 us; speedup 1.0000x reference)
//
#include <hip/hip_runtime.h>

// Quadrilinear (4-D separable linear) upsample, align_corners=True.
// in : [1, 16, 5, 5, 128, 128] f32
// out: [1, 16, 8, 8, 256, 256] f32
//
// Strategy: one block per (c, x_out, y_out). Blend the 4 (x,y) corner planes
// into a single XY-interpolated [128][128] plane in LDS (64 KB), then do a
// bilinear 128^2 -> 256^2 upsample out of LDS with float4 coalesced stores.

constexpr int C  = 16;
constexpr int IX = 5,  IY = 5,  IU = 128, IV = 128;
constexpr int OX = 8,  OY = 8,  OU = 256, OV = 256;

__global__ __launch_bounds__(256) void interp4d(const float* __restrict__ in,
                                                float* __restrict__ out) {
    __shared__ float plane[IU * IV];  // 64 KB

    const int b  = blockIdx.x;
    const int c  = b >> 6;
    const int xo = (b >> 3) & 7;
    const int yo = b & 7;

    // X / Y axis: in=5, out=8, align_corners -> scale = 4/7
    const float sxy = (float)(4.0 / 7.0);
    float cx = (float)xo * sxy;
    int   x0 = (int)cx;            x0 = x0 > IX - 1 ? IX - 1 : x0;
    int   x1 = x0 + 1 < IX ? x0 + 1 : IX - 1;
    float wx = cx - (float)x0;

    float cy = (float)yo * sxy;
    int   y0 = (int)cy;            y0 = y0 > IY - 1 ? IY - 1 : y0;
    int   y1 = y0 + 1 < IY ? y0 + 1 : IY - 1;
    float wy = cy - (float)y0;

    const float w00 = (1.f - wx) * (1.f - wy);
    const float w01 = (1.f - wx) * wy;
    const float w10 = wx * (1.f - wy);
    const float w11 = wx * wy;

    const size_t planeSz = (size_t)IU * IV;
    const float4* p00 = (const float4*)(in + ((size_t)(c * IX + x0) * IY + y0) * planeSz);
    const float4* p01 = (const float4*)(in + ((size_t)(c * IX + x0) * IY + y1) * planeSz);
    const float4* p10 = (const float4*)(in + ((size_t)(c * IX + x1) * IY + y0) * planeSz);
    const float4* p11 = (const float4*)(in + ((size_t)(c * IX + x1) * IY + y1) * planeSz);

    float4* lp = (float4*)plane;
    for (int i = threadIdx.x; i < (int)(planeSz / 4); i += 256) {
        float4 a  = p00[i];
        float4 b2 = p01[i];
        float4 c2 = p10[i];
        float4 d2 = p11[i];
        float4 r;
        r.x = w00 * a.x + w01 * b2.x + w10 * c2.x + w11 * d2.x;
        r.y = w00 * a.y + w01 * b2.y + w10 * c2.y + w11 * d2.y;
        r.z = w00 * a.z + w01 * b2.z + w10 * c2.z + w11 * d2.z;
        r.w = w00 * a.w + w01 * b2.w + w10 * c2.w + w11 * d2.w;
        lp[i] = r;
    }
    __syncthreads();

    // U / V axis: in=128, out=256, align_corners -> scale = 127/255
    const float suv  = (float)(127.0 / 255.0);
    const int   lane = threadIdx.x & 63;
    const int   wg   = threadIdx.x >> 6;   // wave id 0..3 -> u-row group

    // Per-lane V coordinates for its 4 consecutive v_out (fixed across rows)
    int   vi0[4], vi1[4];
    float vw[4];
#pragma unroll
    for (int j = 0; j < 4; ++j) {
        int   vo = lane * 4 + j;
        float cv = (float)vo * suv;
        int   v0 = (int)cv;        v0 = v0 > IV - 1 ? IV - 1 : v0;
        vi0[j] = v0;
        vi1[j] = v0 + 1 < IV ? v0 + 1 : IV - 1;
        vw[j]  = cv - (float)v0;
    }

    float* obase = out + ((((size_t)c * OX + xo) * OY + yo) * OU) * OV;

    for (int uo = wg; uo < OU; uo += 4) {
        float cu = (float)uo * suv;
        int   u0 = (int)cu;        u0 = u0 > IU - 1 ? IU - 1 : u0;
        int   u1 = u0 + 1 < IU ? u0 + 1 : IU - 1;
        float wu = cu - (float)u0;

        const float* r0 = plane + u0 * IV;
        const float* r1 = plane + u1 * IV;

        float tmp[4];
#pragma unroll
        for (int j = 0; j < 4; ++j) {
            float a  = r0[vi0[j]];
            float bb = r0[vi1[j]];
            float cc = r1[vi0[j]];
            float dd = r1[vi1[j]];
            float t0 = a  + (cc - a ) * wu;   // lerp along U at v0
            float t1 = bb + (dd - bb) * wu;   // lerp along U at v1
            tmp[j]   = t0 + (t1 - t0) * vw[j];  // lerp along V
        }
        float4 res;
        res.x = tmp[0]; res.y = tmp[1]; res.z = tmp[2]; res.w = tmp[3];
        ((float4*)(obase + (size_t)uo * OV))[lane] = res;
    }
}

extern "C" void kernel_launch(void* const* d_in, const int* in_sizes, int n_in,
                              void* d_out, int out_size, void* d_ws, size_t ws_size,
                              hipStream_t stream) {
    const float* in  = (const float*)d_in[0];
    float*       out = (float*)d_out;
    interp4d<<<dim3(C * OX * OY), dim3(256), 0, stream>>>(in, out);
}

// Round 3
// 58.233 us; speedup vs baseline: 1.7790x; 1.7790x over previous
//
#include <hip/hip_runtime.h>

// Quadrilinear (4-D separable linear) upsample, align_corners=True.
// in : [1, 16, 5, 5, 128, 128] f32
// out: [1, 16, 8, 8, 256, 256] f32
//
// R2: one block per (c, x_out, y_out, u_quarter). Stage only the 34
// XY-blended input U-rows this quarter needs into LDS (17 KB) -> 8 blocks/CU
// resident (vs 2 with the full 64 KB plane), full 32-wave occupancy.
// Output stores are nontemporal (pure write stream, never re-read) via a
// native ext_vector_type (HIP float4 struct is rejected by the builtin).

constexpr int C  = 16;
constexpr int IX = 5,  IY = 5,  IU = 128, IV = 128;
constexpr int OX = 8,  OY = 8,  OU = 256, OV = 256;
constexpr int QROWS = 64;          // output U rows per block
constexpr int SROWS = 34;          // staged input U rows per block

typedef float floatx4 __attribute__((ext_vector_type(4)));

__global__ __launch_bounds__(256) void interp4d(const float* __restrict__ in,
                                                float* __restrict__ out) {
    __shared__ float plane[SROWS * IV];   // 17 KB

    const int b  = blockIdx.x;
    const int q  = b & 3;           // U-quarter
    const int yo = (b >> 2) & 7;
    const int xo = (b >> 5) & 7;
    const int c  = b >> 8;

    // X / Y axis: in=5, out=8, align_corners -> scale = 4/7
    const float sxy = (float)(4.0 / 7.0);
    float cx = (float)xo * sxy;
    int   x0 = (int)cx;            x0 = x0 > IX - 1 ? IX - 1 : x0;
    int   x1 = x0 + 1 < IX ? x0 + 1 : IX - 1;
    float wx = cx - (float)x0;

    float cy = (float)yo * sxy;
    int   y0 = (int)cy;            y0 = y0 > IY - 1 ? IY - 1 : y0;
    int   y1 = y0 + 1 < IY ? y0 + 1 : IY - 1;
    float wy = cy - (float)y0;

    const float w00 = (1.f - wx) * (1.f - wy);
    const float w01 = (1.f - wx) * wy;
    const float w10 = wx * (1.f - wy);
    const float w11 = wx * wy;

    // U / V axis: in=128, out=256, align_corners -> scale = 127/255
    const float suv = (float)(127.0 / 255.0);

    const int ubase = (int)((float)(q * QROWS) * suv);  // first staged input row

    const size_t planeSz = (size_t)IU * IV;
    const floatx4* p00 = (const floatx4*)(in + ((size_t)(c * IX + x0) * IY + y0) * planeSz);
    const floatx4* p01 = (const floatx4*)(in + ((size_t)(c * IX + x0) * IY + y1) * planeSz);
    const floatx4* p10 = (const floatx4*)(in + ((size_t)(c * IX + x1) * IY + y0) * planeSz);
    const floatx4* p11 = (const floatx4*)(in + ((size_t)(c * IX + x1) * IY + y1) * planeSz);

    // Stage SROWS rows (each 32 float4), XY-blended, into LDS.
    floatx4* lp = (floatx4*)plane;
    for (int i = threadIdx.x; i < SROWS * (IV / 4); i += 256) {
        int r  = i >> 5;            // local row
        int cl = i & 31;            // float4 column
        int gr = ubase + r;  gr = gr > IU - 1 ? IU - 1 : gr;
        int gi = gr * (IV / 4) + cl;
        floatx4 a  = p00[gi];
        floatx4 b2 = p01[gi];
        floatx4 c2 = p10[gi];
        floatx4 d2 = p11[gi];
        lp[i] = w00 * a + w01 * b2 + w10 * c2 + w11 * d2;
    }
    __syncthreads();

    const int lane = threadIdx.x & 63;
    const int wg   = threadIdx.x >> 6;   // wave id 0..3

    // Per-lane V coordinates for its 4 consecutive v_out (fixed across rows)
    int   vi0[4], vi1[4];
    float vw[4];
#pragma unroll
    for (int j = 0; j < 4; ++j) {
        int   vo = lane * 4 + j;
        float cv = (float)vo * suv;
        int   v0 = (int)cv;        v0 = v0 > IV - 1 ? IV - 1 : v0;
        vi0[j] = v0;
        vi1[j] = v0 + 1 < IV ? v0 + 1 : IV - 1;
        vw[j]  = cv - (float)v0;
    }

    float* obase = out + (((size_t)(c * OX + xo) * OY + yo) * OU + q * QROWS) * OV;

    for (int ul = wg; ul < QROWS; ul += 4) {
        int   uo = q * QROWS + ul;
        float cu = (float)uo * suv;
        int   u0 = (int)cu;        u0 = u0 > IU - 1 ? IU - 1 : u0;
        int   u1 = u0 + 1 < IU ? u0 + 1 : IU - 1;
        float wu = cu - (float)u0;

        const float* r0 = plane + (u0 - ubase) * IV;
        const float* r1 = plane + (u1 - ubase) * IV;

        float tmp[4];
#pragma unroll
        for (int j = 0; j < 4; ++j) {
            float a  = r0[vi0[j]];
            float bb = r0[vi1[j]];
            float cc = r1[vi0[j]];
            float dd = r1[vi1[j]];
            float t0 = a  + (cc - a ) * wu;     // lerp along U at v0
            float t1 = bb + (dd - bb) * wu;     // lerp along U at v1
            tmp[j]   = t0 + (t1 - t0) * vw[j];  // lerp along V
        }
        floatx4 res;
        res.x = tmp[0]; res.y = tmp[1]; res.z = tmp[2]; res.w = tmp[3];
        __builtin_nontemporal_store(res, (floatx4*)(obase + (size_t)ul * OV) + lane);
    }
}

extern "C" void kernel_launch(void* const* d_in, const int* in_sizes, int n_in,
                              void* d_out, int out_size, void* d_ws, size_t ws_size,
                              hipStream_t stream) {
    const float* in  = (const float*)d_in[0];
    float*       out = (float*)d_out;
    interp4d<<<dim3(C * OX * OY * 4), dim3(256), 0, stream>>>(in, out);
}

// Round 4
// 57.663 us; speedup vs baseline: 1.7966x; 1.0099x over previous
//
#include <hip/hip_runtime.h>

// Quadrilinear upsample, align_corners=True.
// in : [1, 16, 5, 5, 128, 128] f32 -> out: [1, 16, 8, 8, 256, 256] f32
//
// R4: block = (c, xo-pair, yo-pair, u-quarter). Consecutive (xo,yo) pairs
// share the same 4 input corner planes, so one block reads the 4 raw corner
// quarters ONCE (278 KB) and stages FOUR xy-blended quarter planes in LDS
// (68 KB) -> L2 read traffic drops 4x (1.14 GB -> 285 MB). Inner loop:
// per-lane dedupe — the 4 outputs need only elements [a..a+3] of each input
// row -> 4 contiguous ds_read_b32 per row (offset imms), U-lerp first, then
// V-lerp with precomputed cndmask selects. Nontemporal dwordx4 stores.

constexpr int C  = 16;
constexpr int IX = 5,  IY = 5,  IU = 128, IV = 128;
constexpr int OX = 8,  OY = 8,  OU = 256, OV = 256;
constexpr int QROWS = 64;          // output U rows per quarter
constexpr int SROWS = 34;          // staged input U rows per quarter
constexpr int PLANE = SROWS * IV;  // 4352 floats per blended plane

typedef float floatx4 __attribute__((ext_vector_type(4)));

__global__ __launch_bounds__(256) void interp4d(const float* __restrict__ in,
                                                float* __restrict__ out) {
    __shared__ float lds[4 * PLANE + 4];   // 4 blended planes + zero pad

    const int b  = blockIdx.x;
    const int q  = b & 3;            // u-quarter
    const int yp = (b >> 2) & 3;     // yo-pair
    const int xp = (b >> 4) & 3;     // xo-pair
    const int c  = b >> 6;

    const float sxy = 4.0f / 7.0f;
    const float suv = 127.0f / 255.0f;

    // X pair: combos dx=0,1 -> xo = 2*xp+dx. Shared plane pair (xp0, xp1);
    // per-combo weight on xp1 (alpha): wx if x0==xp0, 1.0 if x0 clamped up.
    float ax[2]; int xp0;
    {
        float cx = (float)(2 * xp) * sxy;
        int x0 = (int)cx; x0 = x0 > IX - 1 ? IX - 1 : x0;
        xp0 = x0; ax[0] = cx - (float)x0;
        cx = (float)(2 * xp + 1) * sxy;
        x0 = (int)cx; x0 = x0 > IX - 1 ? IX - 1 : x0;
        ax[1] = (x0 > xp0) ? 1.0f : (cx - (float)x0);
    }
    const int xp1 = xp0 + 1 < IX ? xp0 + 1 : IX - 1;

    float ay[2]; int yp0;
    {
        float cy = (float)(2 * yp) * sxy;
        int y0 = (int)cy; y0 = y0 > IY - 1 ? IY - 1 : y0;
        yp0 = y0; ay[0] = cy - (float)y0;
        cy = (float)(2 * yp + 1) * sxy;
        y0 = (int)cy; y0 = y0 > IY - 1 ? IY - 1 : y0;
        ay[1] = (y0 > yp0) ? 1.0f : (cy - (float)y0);
    }
    const int yp1 = yp0 + 1 < IY ? yp0 + 1 : IY - 1;

    const int ubase = (int)((float)(q * QROWS) * suv);   // first staged row

    const size_t psz = (size_t)IU * IV;
    const floatx4* p00 = (const floatx4*)(in + ((size_t)(c * IX + xp0) * IY + yp0) * psz);
    const floatx4* p01 = (const floatx4*)(in + ((size_t)(c * IX + xp0) * IY + yp1) * psz);
    const floatx4* p10 = (const floatx4*)(in + ((size_t)(c * IX + xp1) * IY + yp0) * psz);
    const floatx4* p11 = (const floatx4*)(in + ((size_t)(c * IX + xp1) * IY + yp1) * psz);

    if (threadIdx.x < 4) lds[4 * PLANE + threadIdx.x] = 0.0f;  // zero the pad

    // Stage: read 4 raw corner quarters once, emit 4 xy-blended planes.
    floatx4* lp = (floatx4*)lds;
    for (int i = threadIdx.x; i < SROWS * (IV / 4); i += 256) {
        int r  = i >> 5;
        int gr = ubase + r; gr = gr > IU - 1 ? IU - 1 : gr;
        int gi = gr * (IV / 4) + (i & 31);
        floatx4 a00 = p00[gi], a01 = p01[gi], a10 = p10[gi], a11 = p11[gi];
#pragma unroll
        for (int dy = 0; dy < 2; ++dy) {
            floatx4 q0 = a00 + (a01 - a00) * ay[dy];   // y-lerp at xp0
            floatx4 q1 = a10 + (a11 - a10) * ay[dy];   // y-lerp at xp1
#pragma unroll
            for (int dx = 0; dx < 2; ++dx) {
                lp[(dx * 2 + dy) * (PLANE / 4) + i] = q0 + (q1 - q0) * ax[dx];
            }
        }
    }
    __syncthreads();

    const int lane = threadIdx.x & 63;
    const int wg   = threadIdx.x >> 6;

    // Per-lane V setup: outputs vo=4*lane+j need elements [a_ .. a_+3] only
    // (span proof: 3*suv < 1.5 -> v0[3]-v0[0] <= 2, +1 for v1 -> 4 elems).
    int a_; float vw0, vw1, vw2, vw3; int s1, s2, s3;
    {
        float cv = (float)(4 * lane) * suv;
        int v0 = (int)cv; v0 = v0 > IV - 1 ? IV - 1 : v0;
        a_ = v0; vw0 = cv - (float)v0;
        cv = (float)(4 * lane + 1) * suv;
        v0 = (int)cv; v0 = v0 > IV - 1 ? IV - 1 : v0;
        s1 = v0 - a_; vw1 = cv - (float)v0;
        cv = (float)(4 * lane + 2) * suv;
        v0 = (int)cv; v0 = v0 > IV - 1 ? IV - 1 : v0;
        s2 = v0 - a_; vw2 = cv - (float)v0;
        cv = (float)(4 * lane + 3) * suv;
        v0 = (int)cv; v0 = v0 > IV - 1 ? IV - 1 : v0;
        s3 = v0 - a_; vw3 = cv - (float)v0;
    }
    const bool c1a = (s1 == 0), c1b = (s1 == 1);
    const bool c2a = (s2 == 0), c2b = (s2 == 1);
    const bool c3a = (s3 == 0), c3b = (s3 == 1);

    float* ob[4];
#pragma unroll
    for (int m = 0; m < 4; ++m) {
        int xo = 2 * xp + (m >> 1), yo = 2 * yp + (m & 1);
        ob[m] = out + (((size_t)(c * OX + xo) * OY + yo) * OU + q * QROWS) * OV;
    }

    for (int ul = wg; ul < QROWS; ul += 4) {
        int   uo = q * QROWS + ul;
        float cu = (float)uo * suv;
        int   u0 = (int)cu; u0 = u0 > IU - 1 ? IU - 1 : u0;
        int   u1 = u0 + 1 < IU ? u0 + 1 : IU - 1;
        float wu = cu - (float)u0;
        const int lr0 = (u0 - ubase) * IV + a_;
        const int lr1 = (u1 - ubase) * IV + a_;
#pragma unroll
        for (int m = 0; m < 4; ++m) {
            const float* r0 = lds + m * PLANE + lr0;
            const float* r1 = lds + m * PLANE + lr1;
            float f0 = r0[0], f1 = r0[1], f2 = r0[2], f3 = r0[3];
            float h0 = r1[0], h1 = r1[1], h2 = r1[2], h3 = r1[3];
            // U-lerp the 4 unique elements first
            float g0 = f0 + (h0 - f0) * wu;
            float g1 = f1 + (h1 - f1) * wu;
            float g2 = f2 + (h2 - f2) * wu;
            float g3 = f3 + (h3 - f3) * wu;
            // V-lerp with per-lane static selects (loop-invariant masks)
            float x01 = c1a ? g0 : (c1b ? g1 : g2);
            float x11 = c1a ? g1 : (c1b ? g2 : g3);
            float x02 = c2a ? g0 : (c2b ? g1 : g2);
            float x12 = c2a ? g1 : (c2b ? g2 : g3);
            float x03 = c3a ? g0 : (c3b ? g1 : g2);
            float x13 = c3a ? g1 : (c3b ? g2 : g3);
            floatx4 res;
            res.x = g0  + (g1  - g0 ) * vw0;
            res.y = x01 + (x11 - x01) * vw1;
            res.z = x02 + (x12 - x02) * vw2;
            res.w = x03 + (x13 - x03) * vw3;
            __builtin_nontemporal_store(res, (floatx4*)(ob[m] + (size_t)ul * OV) + lane);
        }
    }
}

extern "C" void kernel_launch(void* const* d_in, const int* in_sizes, int n_in,
                              void* d_out, int out_size, void* d_ws, size_t ws_size,
                              hipStream_t stream) {
    const float* in  = (const float*)d_in[0];
    float*       out = (float*)d_out;
    interp4d<<<dim3(C * 4 * 4 * 4), dim3(256), 0, stream>>>(in, out);
}